// Round 12
// baseline (302.022 us; speedup 1.0000x reference)
//
#include <hip/hip_runtime.h>

#define F 64
#define TILE 8192         // edges per bin block (8/thread)
#define NB 1024           // buckets = dst >> 5
#define ROWSB 32          // dst rows per bucket
#define CAP1 2560         // stage-1 bucket capacity (mean 1953, +13.7 sigma)
#define CAP2 1408         // stage-2 bucket capacity (mean 977, +13.8 sigma)
#define HS 68             // LDS row stride (floats)

// precomputed weight-fragment offsets (ushort units) within wp
#define WP1AH 0
#define WP1AL 4096
#define WP1BH 8192
#define WP1BL 12288
#define WP2AH 16384
#define WP2AL 20480

typedef __attribute__((ext_vector_type(8))) short bf8;
typedef __attribute__((ext_vector_type(4))) float f4;
typedef __attribute__((ext_vector_type(2))) float fl2;

__device__ __forceinline__ unsigned short f2bf(float f) {
    unsigned u = __float_as_uint(f);
    unsigned r = u + 0x7fffu + ((u >> 16) & 1u);
    return (unsigned short)(r >> 16);
}
__device__ __forceinline__ float bf2f(unsigned short h) {
    return __uint_as_float((unsigned)h << 16);
}
__device__ __forceinline__ fl2 unpack2(unsigned d) {
    fl2 r;
    r.x = __uint_as_float(d << 16);
    r.y = __uint_as_float(d & 0xffff0000u);
    return r;
}

// Block-wide exclusive prefix over 1024 per-thread counts (16 waves).
__device__ __forceinline__ int block_scan_1024(int c, int tid, int* scratch) {
    int lane = tid & 63, wv = tid >> 6;
    int s = c;
    #pragma unroll
    for (int off = 1; off < 64; off <<= 1) {
        int u = __shfl_up(s, off);
        if (lane >= off) s += u;
    }
    if (lane == 63) scratch[wv] = s;
    __syncthreads();
    if (tid < 64) {
        int ws = (tid < 16) ? scratch[tid] : 0;
        int t = ws;
        #pragma unroll
        for (int off = 1; off < 16; off <<= 1) {
            int u = __shfl_up(t, off);
            if (tid >= off) t += u;
        }
        if (tid < 16) scratch[16 + tid] = t - ws;
    }
    __syncthreads();
    return s - c + scratch[16 + wv];
}

// ================= prep: weights + bin1 + bin2 + cvt (grid-strided x4) =================
// bin passes additionally accumulate global per-row edge counts (rowcnt1/2),
// letting sg1/sg2 skip their block-local histogram pass entirely.
__global__ __launch_bounds__(1024) void prep_kernel(
    const float4* __restrict__ xs4, ushort4* __restrict__ xsb4, int n4,
    const int* __restrict__ src1, const int* __restrict__ dst1,
    const float* __restrict__ ea, int E1,
    int* __restrict__ cur1, uint2* __restrict__ keyA1, int* __restrict__ rowcnt1,
    const int* __restrict__ src2, const int* __restrict__ dst2, int E2,
    int* __restrict__ cur2, unsigned* __restrict__ keyA2, int* __restrict__ rowcnt2,
    const float* __restrict__ W1a, const float* __restrict__ W1b,
    const float* __restrict__ W2a, ushort* __restrict__ wp,
    int nBin1, int nBin2)
{
    __shared__ uint2 stage[TILE];          // 64 KB (bin2 reuses as unsigned*)
    __shared__ int hist[NB], lcur[NB], comb[NB]; // 12 KB
    __shared__ int scratch[32];
    int bid = blockIdx.x;
    int tid = threadIdx.x;

    if (bid == 0) {
        // hi/lo bf16 weight fragment pre-decomposition.
        // frag id: col=fid&15, quad=(fid>>4)&3, c=(fid>>6)&3, kh=(fid>>8)&1
        int fid = tid & 511;
        int col = fid & 15, quad = (fid >> 4) & 3, c = (fid >> 6) & 3, kh = (fid >> 8) & 1;
        const float* Wsrc = (tid < 512) ? W1a : W1b;
        ushort* dh = wp + ((tid < 512) ? WP1AH : WP1BH);
        ushort* dl = wp + ((tid < 512) ? WP1AL : WP1BL);
        #pragma unroll
        for (int j = 0; j < 8; ++j) {
            int k = kh * 32 + quad * 8 + j;
            float w = Wsrc[k * F + c * 16 + col];
            unsigned short hi = f2bf(w);
            dh[fid * 8 + j] = hi;
            dl[fid * 8 + j] = f2bf(w - bf2f(hi));
        }
        if (tid < 512) {
            #pragma unroll
            for (int j = 0; j < 8; ++j) {
                int k = kh * 32 + quad * 8 + j;
                float w = W2a[k * F + c * 16 + col];
                unsigned short hi = f2bf(w);
                wp[WP2AH + fid * 8 + j] = hi;
                wp[WP2AL + fid * 8 + j] = f2bf(w - bf2f(hi));
            }
        }
        return;
    }

    if (bid <= nBin1) {
        int base = (bid - 1) * TILE;
        int cnt = min(TILE, E1 - base);
        hist[tid] = 0;
        __syncthreads();
        int myb[8]; unsigned msd[8], mpk[8];
        #pragma unroll
        for (int j = 0; j < 8; ++j) {
            int idx = tid + 1024 * j;
            if (idx < cnt) {
                int d = dst1[base + idx];
                int s = src1[base + idx];
                float2 e2 = ((const float2* __restrict__)ea)[base + idx];
                myb[j] = d >> 5;
                msd[j] = ((unsigned)s << 16) | (unsigned)d;
                mpk[j] = ((unsigned)f2bf(e2.y) << 16) | (unsigned)f2bf(e2.x);
                atomicAdd(&hist[myb[j]], 1);
                atomicAdd(&rowcnt1[d], 1);
            } else myb[j] = -1;
        }
        __syncthreads();
        int c = hist[tid];
        int gb = CAP1 * tid + atomicAdd(&cur1[tid], c);
        int excl = block_scan_1024(c, tid, scratch);
        comb[tid] = gb - excl;
        lcur[tid] = excl;
        __syncthreads();
        #pragma unroll
        for (int j = 0; j < 8; ++j) {
            if (myb[j] >= 0) {
                int p = atomicAdd(&lcur[myb[j]], 1);
                stage[p] = make_uint2(msd[j], mpk[j]);
            }
        }
        __syncthreads();
        #pragma unroll
        for (int j = 0; j < 8; ++j) {
            int p = tid + 1024 * j;
            if (p < cnt) {
                uint2 f = stage[p];
                int b = (int)(f.x & 0xffffu) >> 5;
                keyA1[comb[b] + p] = f;
            }
        }
        return;
    }

    if (bid <= nBin1 + nBin2) {
        unsigned* ustage = (unsigned*)stage;
        int base = (bid - 1 - nBin1) * TILE;
        int cnt = min(TILE, E2 - base);
        hist[tid] = 0;
        __syncthreads();
        int myb[8]; unsigned msd[8];
        #pragma unroll
        for (int j = 0; j < 8; ++j) {
            int idx = tid + 1024 * j;
            if (idx < cnt) {
                int d = dst2[base + idx];
                int s = src2[base + idx];
                myb[j] = d >> 5;
                msd[j] = ((unsigned)s << 16) | (unsigned)d;
                atomicAdd(&hist[myb[j]], 1);
                atomicAdd(&rowcnt2[d], 1);
            } else myb[j] = -1;
        }
        __syncthreads();
        int c = hist[tid];
        int gb = CAP2 * tid + atomicAdd(&cur2[tid], c);
        int excl = block_scan_1024(c, tid, scratch);
        comb[tid] = gb - excl;
        lcur[tid] = excl;
        __syncthreads();
        #pragma unroll
        for (int j = 0; j < 8; ++j) {
            if (myb[j] >= 0) {
                int p = atomicAdd(&lcur[myb[j]], 1);
                ustage[p] = msd[j];
            }
        }
        __syncthreads();
        #pragma unroll
        for (int j = 0; j < 8; ++j) {
            int p = tid + 1024 * j;
            if (p < cnt) {
                unsigned f = ustage[p];
                int b = (int)(f & 0xffffu) >> 5;
                keyA2[comb[b] + p] = f;
            }
        }
        return;
    }

    {
        // cvt: 4 chunks per block (grid-strided) -> 4x fewer blocks
        int base = (bid - 1 - nBin1 - nBin2) * 4096;
        #pragma unroll
        for (int k = 0; k < 4; ++k) {
            int i = base + k * 1024 + tid;
            if (i < n4) {
                float4 v = xs4[i];
                ushort4 o;
                o.x = f2bf(v.x); o.y = f2bf(v.y); o.z = f2bf(v.z); o.w = f2bf(v.w);
                xsb4[i] = o;
            }
        }
    }
}

// ================= sg1 + mlp1 fused: (histogram-free sort) gather -> MFMA MLP -> x1b =================
__global__ __launch_bounds__(512) void sg1_kernel(
    const uint2* __restrict__ keyA,
    const ushort* __restrict__ xsb,
    const float* __restrict__ x_task,
    const float* __restrict__ We, const float* __restrict__ be,
    const int* __restrict__ gcursor, const int* __restrict__ rowcnt,
    const ushort* __restrict__ wp,
    const float* __restrict__ b1a, const float* __restrict__ b1b,
    ushort* __restrict__ x1b, int n)
{
    __shared__ uint2 lpay[CAP1];           // 20 KB
    __shared__ int hh[ROWSB], rst[ROWSB], cur[ROWSB];
    __shared__ float htile[ROWSB * HS];    // 8.7 KB fp32 h rows
    __shared__ float ltile[2 * 16 * HS];   // 8.7 KB mlp intermediate (per tail wave)
    int tid = threadIdx.x;
    int b = blockIdx.x;
    int cnt = min(gcursor[b], CAP1);
    const uint2* ka = keyA + (size_t)b * CAP1;

    // other waves load keys while wave 0 loads per-row counts + scans
    uint2 myk[5];
    #pragma unroll
    for (int j = 0; j < 5; ++j) {
        int idx = tid + 512 * j;
        if (idx < cnt) myk[j] = ka[idx];
    }
    if (tid < 64) {
        int cc = (tid < ROWSB) ? rowcnt[b * ROWSB + tid] : 0;
        int s = cc;
        #pragma unroll
        for (int off = 1; off < ROWSB; off <<= 1) {
            int u = __shfl_up(s, off);
            if (tid >= off) s += u;
        }
        if (tid < ROWSB) { hh[tid] = cc; rst[tid] = s - cc; cur[tid] = s - cc; }
    }
    __syncthreads();
    #pragma unroll
    for (int j = 0; j < 5; ++j) {
        int idx = tid + 512 * j;
        if (idx < cnt) {
            int p = atomicAdd(&cur[myk[j].x & 31u], 1);
            lpay[p] = myk[j];
        }
    }
    __syncthreads();

    int wave = tid >> 6, lane = tid & 63;
    int q = lane & 7, g = lane >> 3;
    int gid = (wave << 3) | g;     // 0..63
    int r   = gid >> 1;            // row 0..31
    int h   = gid & 1;             // which half of the edge list
    int row = b * ROWSB + r;

    // hoisted x_task row load (off the post-loop critical path)
    float4 xt0 = {0.f, 0.f, 0.f, 0.f}, xt1 = {0.f, 0.f, 0.f, 0.f};
    if (h == 0 && row < n) {
        const float4* xt = (const float4* __restrict__)(x_task + (size_t)row * F + q * 8);
        xt0 = xt[0]; xt1 = xt[1];
    }

    fl2 w0p[4], w1p[4], bbp[4];
    {
        float4 a0 = ((const float4* __restrict__)We)[q * 2];
        float4 a1 = ((const float4* __restrict__)We)[q * 2 + 1];
        float4 c0 = ((const float4* __restrict__)(We + F))[q * 2];
        float4 c1 = ((const float4* __restrict__)(We + F))[q * 2 + 1];
        float4 d0 = ((const float4* __restrict__)be)[q * 2];
        float4 d1 = ((const float4* __restrict__)be)[q * 2 + 1];
        w0p[0] = (fl2){a0.x, a0.y}; w0p[1] = (fl2){a0.z, a0.w};
        w0p[2] = (fl2){a1.x, a1.y}; w0p[3] = (fl2){a1.z, a1.w};
        w1p[0] = (fl2){c0.x, c0.y}; w1p[1] = (fl2){c0.z, c0.w};
        w1p[2] = (fl2){c1.x, c1.y}; w1p[3] = (fl2){c1.z, c1.w};
        bbp[0] = (fl2){d0.x, d0.y}; bbp[1] = (fl2){d0.z, d0.w};
        bbp[2] = (fl2){d1.x, d1.y}; bbp[3] = (fl2){d1.z, d1.w};
    }
    const fl2 zero2 = {0.f, 0.f};

    int c  = hh[r];
    int m0 = (c + 1) >> 1;
    int sh = rst[r] + (h ? m0 : 0);
    int m  = h ? (c - m0) : m0;

    fl2 acc2[4];
    #pragma unroll
    for (int p = 0; p < 4; ++p) acc2[p] = zero2;

    unsigned pk0 = 0, pk1 = 0, pk2 = 0, pk3 = 0;
    uint4 xw0 = {0,0,0,0}, xw1 = {0,0,0,0}, xw2 = {0,0,0,0}, xw3 = {0,0,0,0};

    #define SG1_LOAD(J, K)                                                          \
    if ((K) < m) {                                                                  \
        uint2 t = lpay[sh + (K)];                                                   \
        pk##J = t.y;                                                                \
        xw##J = ((const uint4* __restrict__)(xsb + ((size_t)(t.x >> 16) << 6)))[q]; \
    }

    #define SG1_COMP(PK, XW)                                                        \
    {                                                                               \
        fl2 ex = {__uint_as_float((PK) << 16), __uint_as_float((PK) << 16)};        \
        fl2 ey = {__uint_as_float((PK) & 0xffff0000u),                              \
                  __uint_as_float((PK) & 0xffff0000u)};                             \
        fl2 cc, t2;                                                                 \
        cc = __builtin_elementwise_fma(ey, w1p[0], bbp[0]);                         \
        cc = __builtin_elementwise_fma(ex, w0p[0], cc);                             \
        t2 = unpack2((XW).x) + cc;                                                  \
        acc2[0] += __builtin_elementwise_max(t2, zero2);                            \
        cc = __builtin_elementwise_fma(ey, w1p[1], bbp[1]);                         \
        cc = __builtin_elementwise_fma(ex, w0p[1], cc);                             \
        t2 = unpack2((XW).y) + cc;                                                  \
        acc2[1] += __builtin_elementwise_max(t2, zero2);                            \
        cc = __builtin_elementwise_fma(ey, w1p[2], bbp[2]);                         \
        cc = __builtin_elementwise_fma(ex, w0p[2], cc);                             \
        t2 = unpack2((XW).z) + cc;                                                  \
        acc2[2] += __builtin_elementwise_max(t2, zero2);                            \
        cc = __builtin_elementwise_fma(ey, w1p[3], bbp[3]);                         \
        cc = __builtin_elementwise_fma(ex, w0p[3], cc);                             \
        t2 = unpack2((XW).w) + cc;                                                  \
        acc2[3] += __builtin_elementwise_max(t2, zero2);                            \
    }

    SG1_LOAD(0, 0)
    SG1_LOAD(1, 1)
    SG1_LOAD(2, 2)
    SG1_LOAD(3, 3)
    int i = 0;
    for (; i + 4 <= m; i += 4) {
        SG1_COMP(pk0, xw0) SG1_LOAD(0, i + 4)
        SG1_COMP(pk1, xw1) SG1_LOAD(1, i + 5)
        SG1_COMP(pk2, xw2) SG1_LOAD(2, i + 6)
        SG1_COMP(pk3, xw3) SG1_LOAD(3, i + 7)
    }
    if (i < m)     SG1_COMP(pk0, xw0)
    if (i + 1 < m) SG1_COMP(pk1, xw1)
    if (i + 2 < m) SG1_COMP(pk2, xw2)
    #undef SG1_LOAD
    #undef SG1_COMP

    float acc[8];
    #pragma unroll
    for (int p = 0; p < 4; ++p) { acc[2 * p] = acc2[p].x; acc[2 * p + 1] = acc2[p].y; }
    #pragma unroll
    for (int j = 0; j < 8; ++j) acc[j] += __shfl_xor(acc[j], 8);

    if (h == 0 && row < n) {
        float4 o0, o1;
        o0.x = acc[0] + xt0.x; o0.y = acc[1] + xt0.y; o0.z = acc[2] + xt0.z; o0.w = acc[3] + xt0.w;
        o1.x = acc[4] + xt1.x; o1.y = acc[5] + xt1.y; o1.z = acc[6] + xt1.z; o1.w = acc[7] + xt1.w;
        float4* hp = (float4*)&htile[r * HS + q * 8];
        hp[0] = o0; hp[1] = o1;
    }
    __syncthreads();

    // ---- fused mlp1 tail: waves 0,1 each process one 16-row MFMA tile ----
    if (wave < 2) {
        int t = wave;
        int quad = lane >> 4, col = lane & 15;
        float* lt = ltile + t * 16 * HS;

        bf8 Ah[2], Al[2];
        #pragma unroll
        for (int kh = 0; kh < 2; ++kh) {
            const float4* hr4 = (const float4*)&htile[(t * 16 + col) * HS + kh * 32 + quad * 8];
            float4 v0 = hr4[0], v1 = hr4[1];
            float av[8] = {v0.x, v0.y, v0.z, v0.w, v1.x, v1.y, v1.z, v1.w};
            bf8 th, tl;
            #pragma unroll
            for (int j = 0; j < 8; ++j) {
                unsigned short h1 = f2bf(av[j]);
                th[j] = (short)h1; tl[j] = (short)f2bf(av[j] - bf2f(h1));
            }
            Ah[kh] = th; Al[kh] = tl;
        }
        #pragma unroll
        for (int c4i = 0; c4i < 4; ++c4i) {
            int f0 = ((0 * 4 + c4i) * 4 + quad) * 16 + col;
            int f1 = ((1 * 4 + c4i) * 4 + quad) * 16 + col;
            bf8 wh0 = *(const bf8*)(wp + WP1AH + f0 * 8);
            bf8 wl0 = *(const bf8*)(wp + WP1AL + f0 * 8);
            bf8 wh1 = *(const bf8*)(wp + WP1AH + f1 * 8);
            bf8 wl1 = *(const bf8*)(wp + WP1AL + f1 * 8);
            f4 accm = {0.f, 0.f, 0.f, 0.f};
            accm = __builtin_amdgcn_mfma_f32_16x16x32_bf16(Ah[0], wh0, accm, 0, 0, 0);
            accm = __builtin_amdgcn_mfma_f32_16x16x32_bf16(Ah[0], wl0, accm, 0, 0, 0);
            accm = __builtin_amdgcn_mfma_f32_16x16x32_bf16(Al[0], wh0, accm, 0, 0, 0);
            accm = __builtin_amdgcn_mfma_f32_16x16x32_bf16(Ah[1], wh1, accm, 0, 0, 0);
            accm = __builtin_amdgcn_mfma_f32_16x16x32_bf16(Ah[1], wl1, accm, 0, 0, 0);
            accm = __builtin_amdgcn_mfma_f32_16x16x32_bf16(Al[1], wh1, accm, 0, 0, 0);
            float ba = b1a[c4i * 16 + col];
            #pragma unroll
            for (int rr = 0; rr < 4; ++rr)
                lt[(quad * 4 + rr) * HS + c4i * 16 + col] = fmaxf(accm[rr] + ba, 0.f);
        }
        bf8 A2h[2], A2l[2];
        #pragma unroll
        for (int kh = 0; kh < 2; ++kh) {
            const float4* lr4 = (const float4*)&lt[col * HS + kh * 32 + quad * 8];
            float4 v0 = lr4[0], v1 = lr4[1];
            float av[8] = {v0.x, v0.y, v0.z, v0.w, v1.x, v1.y, v1.z, v1.w};
            bf8 th, tl;
            #pragma unroll
            for (int j = 0; j < 8; ++j) {
                unsigned short h1 = f2bf(av[j]);
                th[j] = (short)h1; tl[j] = (short)f2bf(av[j] - bf2f(h1));
            }
            A2h[kh] = th; A2l[kh] = tl;
        }
        #pragma unroll
        for (int c4i = 0; c4i < 4; ++c4i) {
            int f0 = ((0 * 4 + c4i) * 4 + quad) * 16 + col;
            int f1 = ((1 * 4 + c4i) * 4 + quad) * 16 + col;
            bf8 wh0 = *(const bf8*)(wp + WP1BH + f0 * 8);
            bf8 wl0 = *(const bf8*)(wp + WP1BL + f0 * 8);
            bf8 wh1 = *(const bf8*)(wp + WP1BH + f1 * 8);
            bf8 wl1 = *(const bf8*)(wp + WP1BL + f1 * 8);
            f4 accm = {0.f, 0.f, 0.f, 0.f};
            accm = __builtin_amdgcn_mfma_f32_16x16x32_bf16(A2h[0], wh0, accm, 0, 0, 0);
            accm = __builtin_amdgcn_mfma_f32_16x16x32_bf16(A2h[0], wl0, accm, 0, 0, 0);
            accm = __builtin_amdgcn_mfma_f32_16x16x32_bf16(A2l[0], wh0, accm, 0, 0, 0);
            accm = __builtin_amdgcn_mfma_f32_16x16x32_bf16(A2h[1], wh1, accm, 0, 0, 0);
            accm = __builtin_amdgcn_mfma_f32_16x16x32_bf16(A2h[1], wl1, accm, 0, 0, 0);
            accm = __builtin_amdgcn_mfma_f32_16x16x32_bf16(A2l[1], wh1, accm, 0, 0, 0);
            float bb = b1b[c4i * 16 + col];
            #pragma unroll
            for (int rr = 0; rr < 4; ++rr)
                lt[(quad * 4 + rr) * HS + c4i * 16 + col] = accm[rr] + bb;
        }
        int rr = lane >> 2, cc2 = (lane & 3) * 16;
        unsigned o[8];
        #pragma unroll
        for (int j = 0; j < 8; ++j) {
            unsigned lo = f2bf(lt[rr * HS + cc2 + 2 * j]);
            unsigned hi = f2bf(lt[rr * HS + cc2 + 2 * j + 1]);
            o[j] = lo | (hi << 16);
        }
        uint4* dst = (uint4*)(x1b + (size_t)(b * ROWSB + t * 16 + rr) * F + cc2);
        dst[0] = make_uint4(o[0], o[1], o[2], o[3]);
        dst[1] = make_uint4(o[4], o[5], o[6], o[7]);
    }
}

// ================= sg2 + mlp2 fused: (histogram-free sort) gather -> MFMA -> logits =================
__global__ __launch_bounds__(512) void sg2_kernel(
    const unsigned* __restrict__ keyA,
    const ushort* __restrict__ x1b,
    const float* __restrict__ x_actor,
    const int* __restrict__ gcursor, const int* __restrict__ rowcnt,
    const ushort* __restrict__ wp,
    const float* __restrict__ b2a, const float* __restrict__ W2b,
    const float* __restrict__ b2b,
    float* __restrict__ out, int n)
{
    __shared__ unsigned lpay[CAP2];        // 5.5 KB
    __shared__ int hh[ROWSB], rst[ROWSB], cur[ROWSB];
    __shared__ float htile[ROWSB * HS];    // 8.7 KB
    int tid = threadIdx.x;
    int b = blockIdx.x;
    int cnt = min(gcursor[b], CAP2);
    const unsigned* ka = keyA + (size_t)b * CAP2;

    unsigned myk[3];
    #pragma unroll
    for (int j = 0; j < 3; ++j) {
        int idx = tid + 512 * j;
        if (idx < cnt) myk[j] = ka[idx];
    }
    if (tid < 64) {
        int cc = (tid < ROWSB) ? rowcnt[b * ROWSB + tid] : 0;
        int s = cc;
        #pragma unroll
        for (int off = 1; off < ROWSB; off <<= 1) {
            int u = __shfl_up(s, off);
            if (tid >= off) s += u;
        }
        if (tid < ROWSB) { hh[tid] = cc; rst[tid] = s - cc; cur[tid] = s - cc; }
    }
    __syncthreads();
    #pragma unroll
    for (int j = 0; j < 3; ++j) {
        int idx = tid + 512 * j;
        if (idx < cnt) {
            int p = atomicAdd(&cur[myk[j] & 31u], 1);
            lpay[p] = myk[j];
        }
    }
    __syncthreads();

    int wave = tid >> 6, lane = tid & 63;
    int q = lane & 7, g = lane >> 3;
    int gid = (wave << 3) | g;
    int r   = gid >> 1;
    int h   = gid & 1;
    int row = b * ROWSB + r;
    const fl2 zero2 = {0.f, 0.f};

    // hoisted x_actor row load (off the post-loop critical path)
    float4 xt0 = {0.f, 0.f, 0.f, 0.f}, xt1 = {0.f, 0.f, 0.f, 0.f};
    if (h == 0 && row < n) {
        const float4* xt = (const float4* __restrict__)(x_actor + (size_t)row * F + q * 8);
        xt0 = xt[0]; xt1 = xt[1];
    }

    int c  = hh[r];
    int m0 = (c + 1) >> 1;
    int sh = rst[r] + (h ? m0 : 0);
    int m  = h ? (c - m0) : m0;

    fl2 acc2[4];
    #pragma unroll
    for (int p = 0; p < 4; ++p) acc2[p] = zero2;

    uint4 xw0 = {0,0,0,0}, xw1 = {0,0,0,0}, xw2 = {0,0,0,0}, xw3 = {0,0,0,0};

    #define SG2_LOAD(J, K)                                                          \
    if ((K) < m) {                                                                  \
        unsigned t = lpay[sh + (K)];                                                \
        xw##J = ((const uint4* __restrict__)(x1b + ((size_t)(t >> 16) << 6)))[q];   \
    }

    #define SG2_COMP(XW)                                                            \
    {                                                                               \
        acc2[0] += unpack2((XW).x);                                                 \
        acc2[1] += unpack2((XW).y);                                                 \
        acc2[2] += unpack2((XW).z);                                                 \
        acc2[3] += unpack2((XW).w);                                                 \
    }

    SG2_LOAD(0, 0)
    SG2_LOAD(1, 1)
    SG2_LOAD(2, 2)
    SG2_LOAD(3, 3)
    int i = 0;
    for (; i + 4 <= m; i += 4) {
        SG2_COMP(xw0) SG2_LOAD(0, i + 4)
        SG2_COMP(xw1) SG2_LOAD(1, i + 5)
        SG2_COMP(xw2) SG2_LOAD(2, i + 6)
        SG2_COMP(xw3) SG2_LOAD(3, i + 7)
    }
    if (i < m)     SG2_COMP(xw0)
    if (i + 1 < m) SG2_COMP(xw1)
    if (i + 2 < m) SG2_COMP(xw2)
    #undef SG2_LOAD
    #undef SG2_COMP

    float acc[8];
    #pragma unroll
    for (int p = 0; p < 4; ++p) { acc[2 * p] = acc2[p].x; acc[2 * p + 1] = acc2[p].y; }
    #pragma unroll
    for (int j = 0; j < 8; ++j) acc[j] += __shfl_xor(acc[j], 8);

    if (h == 0 && row < n) {
        float4 o0, o1;
        o0.x = acc[0] + xt0.x; o0.y = acc[1] + xt0.y; o0.z = acc[2] + xt0.z; o0.w = acc[3] + xt0.w;
        o1.x = acc[4] + xt1.x; o1.y = acc[5] + xt1.y; o1.z = acc[6] + xt1.z; o1.w = acc[7] + xt1.w;
        float4* hp = (float4*)&htile[r * HS + q * 8];
        hp[0] = o0; hp[1] = o1;
    }
    __syncthreads();

    // ---- fused mlp2 tail: waves 0,1 each process one 16-row MFMA tile ----
    if (wave < 2) {
        int t = wave;
        int quad = lane >> 4, col = lane & 15;

        bf8 Ah[2], Al[2];
        #pragma unroll
        for (int kh = 0; kh < 2; ++kh) {
            const float4* hr4 = (const float4*)&htile[(t * 16 + col) * HS + kh * 32 + quad * 8];
            float4 v0 = hr4[0], v1 = hr4[1];
            float av[8] = {v0.x, v0.y, v0.z, v0.w, v1.x, v1.y, v1.z, v1.w};
            bf8 th, tl;
            #pragma unroll
            for (int j = 0; j < 8; ++j) {
                unsigned short h1 = f2bf(av[j]);
                th[j] = (short)h1; tl[j] = (short)f2bf(av[j] - bf2f(h1));
            }
            Ah[kh] = th; Al[kh] = tl;
        }

        float partial[4] = {0.f, 0.f, 0.f, 0.f};
        #pragma unroll
        for (int c4i = 0; c4i < 4; ++c4i) {
            int f0 = ((0 * 4 + c4i) * 4 + quad) * 16 + col;
            int f1 = ((1 * 4 + c4i) * 4 + quad) * 16 + col;
            bf8 wh0 = *(const bf8*)(wp + WP2AH + f0 * 8);
            bf8 wl0 = *(const bf8*)(wp + WP2AL + f0 * 8);
            bf8 wh1 = *(const bf8*)(wp + WP2AH + f1 * 8);
            bf8 wl1 = *(const bf8*)(wp + WP2AL + f1 * 8);
            f4 accm = {0.f, 0.f, 0.f, 0.f};
            accm = __builtin_amdgcn_mfma_f32_16x16x32_bf16(Ah[0], wh0, accm, 0, 0, 0);
            accm = __builtin_amdgcn_mfma_f32_16x16x32_bf16(Ah[0], wl0, accm, 0, 0, 0);
            accm = __builtin_amdgcn_mfma_f32_16x16x32_bf16(Al[0], wh0, accm, 0, 0, 0);
            accm = __builtin_amdgcn_mfma_f32_16x16x32_bf16(Ah[1], wh1, accm, 0, 0, 0);
            accm = __builtin_amdgcn_mfma_f32_16x16x32_bf16(Ah[1], wl1, accm, 0, 0, 0);
            accm = __builtin_amdgcn_mfma_f32_16x16x32_bf16(Al[1], wh1, accm, 0, 0, 0);
            float ba = b2a[c4i * 16 + col];
            float w_o = W2b[c4i * 16 + col];
            #pragma unroll
            for (int rr = 0; rr < 4; ++rr)
                partial[rr] += fmaxf(accm[rr] + ba, 0.f) * w_o;
        }
        #pragma unroll
        for (int off = 1; off < 16; off <<= 1)
            #pragma unroll
            for (int rr = 0; rr < 4; ++rr)
                partial[rr] += __shfl_xor(partial[rr], off);
        if (col == 0) {
            float bias2 = b2b[0];
            #pragma unroll
            for (int rr = 0; rr < 4; ++rr)
                out[b * ROWSB + t * 16 + quad * 4 + rr] = partial[rr] + bias2;
        }
    }
}

extern "C" void kernel_launch(void* const* d_in, const int* in_sizes, int n_in,
                              void* d_out, int out_size, void* d_ws, size_t ws_size,
                              hipStream_t stream)
{
    const float* x_state   = (const float*)d_in[0];
    const float* x_task    = (const float*)d_in[1];
    const float* x_actor   = (const float*)d_in[2];
    const float* edge_attr = (const float*)d_in[3];
    const float* We        = (const float*)d_in[4];
    const float* be        = (const float*)d_in[5];
    const float* W1a       = (const float*)d_in[6];
    const float* b1a       = (const float*)d_in[7];
    const float* W1b       = (const float*)d_in[8];
    const float* b1b       = (const float*)d_in[9];
    const float* W2a       = (const float*)d_in[10];
    const float* b2a       = (const float*)d_in[11];
    const float* W2b       = (const float*)d_in[12];
    const float* b2b       = (const float*)d_in[13];
    const int*   src_st    = (const int*)d_in[14];
    const int*   dst_st    = (const int*)d_in[15];
    const int*   src_ta    = (const int*)d_in[16];
    const int*   dst_ta    = (const int*)d_in[17];

    int n_state = in_sizes[0] / F;
    int n_task  = in_sizes[1] / F;
    int n_actor = in_sizes[2] / F;
    int E_st    = in_sizes[14];
    int E_ta    = in_sizes[16];

    // ---- workspace layout (~47.5 MB) ----
    ushort*   x1b     = (ushort*)d_ws;                            // 4 MB (bf16 x1)
    float*    hbig    = (float*)(x1b + (size_t)n_task * F);       // 8 MB region (wp carved from it)
    ushort*   wp      = (ushort*)hbig;                            // 48 KB hi/lo weight fragments
    ushort*   xsb     = (ushort*)(hbig + (size_t)n_task * F);     // 8 MB (bf16 x_state)
    uint2*    keyA1   = (uint2*)(xsb + (size_t)n_state * F);      // 21 MB
    unsigned* keyA2   = (unsigned*)(keyA1 + (size_t)NB * CAP1);   // 5.8 MB
    int*      cur1    = (int*)(keyA2 + (size_t)NB * CAP2);        // [1024]
    int*      cur2    = cur1 + NB;                                // [1024]
    int*      rowcnt1 = cur2 + NB;                                // [n_task]
    int*      rowcnt2 = rowcnt1 + n_task;                         // [n_actor]

    int n4    = n_state * F / 4;
    int nCvt  = (n4 + 4095) / 4096;
    int nBin1 = (E_st + TILE - 1) / TILE;
    int nBin2 = (E_ta + TILE - 1) / TILE;

    hipMemsetAsync(cur1, 0, (size_t)(2 * NB + n_task + n_actor) * sizeof(int), stream);
    prep_kernel<<<1 + nBin1 + nBin2 + nCvt, 1024, 0, stream>>>(
        (const float4*)x_state, (ushort4*)xsb, n4,
        src_st, dst_st, edge_attr, E_st, cur1, keyA1, rowcnt1,
        src_ta, dst_ta, E_ta, cur2, keyA2, rowcnt2,
        W1a, W1b, W2a, wp,
        nBin1, nBin2);
    sg1_kernel<<<NB, 512, 0, stream>>>(
        keyA1, xsb, x_task, We, be, cur1, rowcnt1, wp, b1a, b1b, x1b, n_task);
    sg2_kernel<<<NB, 512, 0, stream>>>(
        keyA2, x1b, x_actor, cur2, rowcnt2, wp, b2a, W2b, b2b, (float*)d_out, n_actor);
}

// Round 13
// 194.663 us; speedup vs baseline: 1.5515x; 1.5515x over previous
//
#include <hip/hip_runtime.h>

#define F 64
#define TILE 8192         // edges per bin block (8/thread)
#define NB 1024           // buckets = dst >> 5
#define ROWSB 32          // dst rows per bucket
#define CAP1 2560         // stage-1 bucket capacity (mean 1953, +13.7 sigma)
#define CAP2 1408         // stage-2 bucket capacity (mean 977, +13.8 sigma)
#define HS 68             // LDS row stride (floats)

// precomputed weight-fragment offsets (ushort units) within wp
#define WP1AH 0
#define WP1AL 4096
#define WP1BH 8192
#define WP1BL 12288
#define WP2AH 16384
#define WP2AL 20480

typedef __attribute__((ext_vector_type(8))) short bf8;
typedef __attribute__((ext_vector_type(4))) float f4;
typedef __attribute__((ext_vector_type(2))) float fl2;

__device__ __forceinline__ unsigned short f2bf(float f) {
    unsigned u = __float_as_uint(f);
    unsigned r = u + 0x7fffu + ((u >> 16) & 1u);
    return (unsigned short)(r >> 16);
}
__device__ __forceinline__ float bf2f(unsigned short h) {
    return __uint_as_float((unsigned)h << 16);
}
__device__ __forceinline__ fl2 unpack2(unsigned d) {
    fl2 r;
    r.x = __uint_as_float(d << 16);
    r.y = __uint_as_float(d & 0xffff0000u);
    return r;
}

// Block-wide exclusive prefix over 1024 per-thread counts (16 waves).
__device__ __forceinline__ int block_scan_1024(int c, int tid, int* scratch) {
    int lane = tid & 63, wv = tid >> 6;
    int s = c;
    #pragma unroll
    for (int off = 1; off < 64; off <<= 1) {
        int u = __shfl_up(s, off);
        if (lane >= off) s += u;
    }
    if (lane == 63) scratch[wv] = s;
    __syncthreads();
    if (tid < 64) {
        int ws = (tid < 16) ? scratch[tid] : 0;
        int t = ws;
        #pragma unroll
        for (int off = 1; off < 16; off <<= 1) {
            int u = __shfl_up(t, off);
            if (tid >= off) t += u;
        }
        if (tid < 16) scratch[16 + tid] = t - ws;
    }
    __syncthreads();
    return s - c + scratch[16 + wv];
}

// ================= prep: weights + bin1 + bin2 + cvt (grid-strided x4) =================
__global__ __launch_bounds__(1024) void prep_kernel(
    const float4* __restrict__ xs4, ushort4* __restrict__ xsb4, int n4,
    const int* __restrict__ src1, const int* __restrict__ dst1,
    const float* __restrict__ ea, int E1,
    int* __restrict__ cur1, uint2* __restrict__ keyA1,
    const int* __restrict__ src2, const int* __restrict__ dst2, int E2,
    int* __restrict__ cur2, unsigned* __restrict__ keyA2,
    const float* __restrict__ W1a, const float* __restrict__ W1b,
    const float* __restrict__ W2a, ushort* __restrict__ wp,
    int nBin1, int nBin2)
{
    __shared__ uint2 stage[TILE];          // 64 KB (bin2 reuses as unsigned*)
    __shared__ int hist[NB], lcur[NB], comb[NB]; // 12 KB
    __shared__ int scratch[32];
    int bid = blockIdx.x;
    int tid = threadIdx.x;

    if (bid == 0) {
        // hi/lo bf16 weight fragment pre-decomposition.
        // frag id: col=fid&15, quad=(fid>>4)&3, c=(fid>>6)&3, kh=(fid>>8)&1
        int fid = tid & 511;
        int col = fid & 15, quad = (fid >> 4) & 3, c = (fid >> 6) & 3, kh = (fid >> 8) & 1;
        const float* Wsrc = (tid < 512) ? W1a : W1b;
        ushort* dh = wp + ((tid < 512) ? WP1AH : WP1BH);
        ushort* dl = wp + ((tid < 512) ? WP1AL : WP1BL);
        #pragma unroll
        for (int j = 0; j < 8; ++j) {
            int k = kh * 32 + quad * 8 + j;
            float w = Wsrc[k * F + c * 16 + col];
            unsigned short hi = f2bf(w);
            dh[fid * 8 + j] = hi;
            dl[fid * 8 + j] = f2bf(w - bf2f(hi));
        }
        if (tid < 512) {
            #pragma unroll
            for (int j = 0; j < 8; ++j) {
                int k = kh * 32 + quad * 8 + j;
                float w = W2a[k * F + c * 16 + col];
                unsigned short hi = f2bf(w);
                wp[WP2AH + fid * 8 + j] = hi;
                wp[WP2AL + fid * 8 + j] = f2bf(w - bf2f(hi));
            }
        }
        return;
    }

    if (bid <= nBin1) {
        int base = (bid - 1) * TILE;
        int cnt = min(TILE, E1 - base);
        hist[tid] = 0;
        __syncthreads();
        int myb[8]; unsigned msd[8], mpk[8];
        #pragma unroll
        for (int j = 0; j < 8; ++j) {
            int idx = tid + 1024 * j;
            if (idx < cnt) {
                int d = dst1[base + idx];
                int s = src1[base + idx];
                float2 e2 = ((const float2* __restrict__)ea)[base + idx];
                myb[j] = d >> 5;
                msd[j] = ((unsigned)s << 16) | (unsigned)d;
                mpk[j] = ((unsigned)f2bf(e2.y) << 16) | (unsigned)f2bf(e2.x);
                atomicAdd(&hist[myb[j]], 1);
            } else myb[j] = -1;
        }
        __syncthreads();
        int c = hist[tid];
        int gb = CAP1 * tid + atomicAdd(&cur1[tid], c);
        int excl = block_scan_1024(c, tid, scratch);
        comb[tid] = gb - excl;
        lcur[tid] = excl;
        __syncthreads();
        #pragma unroll
        for (int j = 0; j < 8; ++j) {
            if (myb[j] >= 0) {
                int p = atomicAdd(&lcur[myb[j]], 1);
                stage[p] = make_uint2(msd[j], mpk[j]);
            }
        }
        __syncthreads();
        #pragma unroll
        for (int j = 0; j < 8; ++j) {
            int p = tid + 1024 * j;
            if (p < cnt) {
                uint2 f = stage[p];
                int b = (int)(f.x & 0xffffu) >> 5;
                keyA1[comb[b] + p] = f;
            }
        }
        return;
    }

    if (bid <= nBin1 + nBin2) {
        unsigned* ustage = (unsigned*)stage;
        int base = (bid - 1 - nBin1) * TILE;
        int cnt = min(TILE, E2 - base);
        hist[tid] = 0;
        __syncthreads();
        int myb[8]; unsigned msd[8];
        #pragma unroll
        for (int j = 0; j < 8; ++j) {
            int idx = tid + 1024 * j;
            if (idx < cnt) {
                int d = dst2[base + idx];
                int s = src2[base + idx];
                myb[j] = d >> 5;
                msd[j] = ((unsigned)s << 16) | (unsigned)d;
                atomicAdd(&hist[myb[j]], 1);
            } else myb[j] = -1;
        }
        __syncthreads();
        int c = hist[tid];
        int gb = CAP2 * tid + atomicAdd(&cur2[tid], c);
        int excl = block_scan_1024(c, tid, scratch);
        comb[tid] = gb - excl;
        lcur[tid] = excl;
        __syncthreads();
        #pragma unroll
        for (int j = 0; j < 8; ++j) {
            if (myb[j] >= 0) {
                int p = atomicAdd(&lcur[myb[j]], 1);
                ustage[p] = msd[j];
            }
        }
        __syncthreads();
        #pragma unroll
        for (int j = 0; j < 8; ++j) {
            int p = tid + 1024 * j;
            if (p < cnt) {
                unsigned f = ustage[p];
                int b = (int)(f & 0xffffu) >> 5;
                keyA2[comb[b] + p] = f;
            }
        }
        return;
    }

    {
        // cvt: 4 chunks per block (grid-strided) -> 4x fewer blocks
        int base = (bid - 1 - nBin1 - nBin2) * 4096;
        #pragma unroll
        for (int k = 0; k < 4; ++k) {
            int i = base + k * 1024 + tid;
            if (i < n4) {
                float4 v = xs4[i];
                ushort4 o;
                o.x = f2bf(v.x); o.y = f2bf(v.y); o.z = f2bf(v.z); o.w = f2bf(v.w);
                xsb4[i] = o;
            }
        }
    }
}

// ================= sg1 + mlp1 fused: gather -> h (LDS) -> 2-wave MFMA MLP -> x1b =================
__global__ __launch_bounds__(512) void sg1_kernel(
    const uint2* __restrict__ keyA,
    const ushort* __restrict__ xsb,
    const float* __restrict__ x_task,
    const float* __restrict__ We, const float* __restrict__ be,
    const int* __restrict__ gcursor,
    const ushort* __restrict__ wp,
    const float* __restrict__ b1a, const float* __restrict__ b1b,
    ushort* __restrict__ x1b, int n)
{
    __shared__ uint2 lpay[CAP1];           // 20 KB
    __shared__ int hh[ROWSB], rst[ROWSB], cur[ROWSB];
    __shared__ float htile[ROWSB * HS];    // 8.7 KB fp32 h rows
    __shared__ float ltile[2 * 16 * HS];   // 8.7 KB mlp intermediate (per tail wave)
    int tid = threadIdx.x;
    int b = blockIdx.x;
    int cnt = min(gcursor[b], CAP1);
    const uint2* ka = keyA + (size_t)b * CAP1;

    uint2 myk[5];
    #pragma unroll
    for (int j = 0; j < 5; ++j) {
        int idx = tid + 512 * j;
        if (idx < cnt) myk[j] = ka[idx];
    }
    if (tid < ROWSB) hh[tid] = 0;
    __syncthreads();
    #pragma unroll
    for (int j = 0; j < 5; ++j) {
        int idx = tid + 512 * j;
        if (idx < cnt) atomicAdd(&hh[myk[j].x & 31u], 1);
    }
    __syncthreads();
    if (tid < 64) {
        int cc = (tid < ROWSB) ? hh[tid] : 0;
        int s = cc;
        #pragma unroll
        for (int off = 1; off < ROWSB; off <<= 1) {
            int u = __shfl_up(s, off);
            if (tid >= off) s += u;
        }
        if (tid < ROWSB) { rst[tid] = s - cc; cur[tid] = s - cc; }
    }
    __syncthreads();
    #pragma unroll
    for (int j = 0; j < 5; ++j) {
        int idx = tid + 512 * j;
        if (idx < cnt) {
            int p = atomicAdd(&cur[myk[j].x & 31u], 1);
            lpay[p] = myk[j];
        }
    }
    __syncthreads();

    int wave = tid >> 6, lane = tid & 63;
    int q = lane & 7, g = lane >> 3;
    int gid = (wave << 3) | g;     // 0..63
    int r   = gid >> 1;            // row 0..31
    int h   = gid & 1;             // which half of the edge list
    int row = b * ROWSB + r;

    // hoist the x_task row load above the gather loop (off the post-loop
    // critical path; consumed only after the pipeline drains)
    float4 xt0 = {0.f, 0.f, 0.f, 0.f}, xt1 = {0.f, 0.f, 0.f, 0.f};
    if (h == 0 && row < n) {
        const float4* xt = (const float4* __restrict__)(x_task + (size_t)row * F + q * 8);
        xt0 = xt[0]; xt1 = xt[1];
    }

    fl2 w0p[4], w1p[4], bbp[4];
    {
        float4 a0 = ((const float4* __restrict__)We)[q * 2];
        float4 a1 = ((const float4* __restrict__)We)[q * 2 + 1];
        float4 c0 = ((const float4* __restrict__)(We + F))[q * 2];
        float4 c1 = ((const float4* __restrict__)(We + F))[q * 2 + 1];
        float4 d0 = ((const float4* __restrict__)be)[q * 2];
        float4 d1 = ((const float4* __restrict__)be)[q * 2 + 1];
        w0p[0] = (fl2){a0.x, a0.y}; w0p[1] = (fl2){a0.z, a0.w};
        w0p[2] = (fl2){a1.x, a1.y}; w0p[3] = (fl2){a1.z, a1.w};
        w1p[0] = (fl2){c0.x, c0.y}; w1p[1] = (fl2){c0.z, c0.w};
        w1p[2] = (fl2){c1.x, c1.y}; w1p[3] = (fl2){c1.z, c1.w};
        bbp[0] = (fl2){d0.x, d0.y}; bbp[1] = (fl2){d0.z, d0.w};
        bbp[2] = (fl2){d1.x, d1.y}; bbp[3] = (fl2){d1.z, d1.w};
    }
    const fl2 zero2 = {0.f, 0.f};

    int c  = hh[r];
    int m0 = (c + 1) >> 1;
    int sh = rst[r] + (h ? m0 : 0);
    int m  = h ? (c - m0) : m0;

    fl2 acc2[4];
    #pragma unroll
    for (int p = 0; p < 4; ++p) acc2[p] = zero2;

    unsigned pk0 = 0, pk1 = 0, pk2 = 0, pk3 = 0;
    uint4 xw0 = {0,0,0,0}, xw1 = {0,0,0,0}, xw2 = {0,0,0,0}, xw3 = {0,0,0,0};

    #define SG1_LOAD(J, K)                                                          \
    if ((K) < m) {                                                                  \
        uint2 t = lpay[sh + (K)];                                                   \
        pk##J = t.y;                                                                \
        xw##J = ((const uint4* __restrict__)(xsb + ((size_t)(t.x >> 16) << 6)))[q]; \
    }

    #define SG1_COMP(PK, XW)                                                        \
    {                                                                               \
        fl2 ex = {__uint_as_float((PK) << 16), __uint_as_float((PK) << 16)};        \
        fl2 ey = {__uint_as_float((PK) & 0xffff0000u),                              \
                  __uint_as_float((PK) & 0xffff0000u)};                             \
        fl2 cc, t2;                                                                 \
        cc = __builtin_elementwise_fma(ey, w1p[0], bbp[0]);                         \
        cc = __builtin_elementwise_fma(ex, w0p[0], cc);                             \
        t2 = unpack2((XW).x) + cc;                                                  \
        acc2[0] += __builtin_elementwise_max(t2, zero2);                            \
        cc = __builtin_elementwise_fma(ey, w1p[1], bbp[1]);                         \
        cc = __builtin_elementwise_fma(ex, w0p[1], cc);                             \
        t2 = unpack2((XW).y) + cc;                                                  \
        acc2[1] += __builtin_elementwise_max(t2, zero2);                            \
        cc = __builtin_elementwise_fma(ey, w1p[2], bbp[2]);                         \
        cc = __builtin_elementwise_fma(ex, w0p[2], cc);                             \
        t2 = unpack2((XW).z) + cc;                                                  \
        acc2[2] += __builtin_elementwise_max(t2, zero2);                            \
        cc = __builtin_elementwise_fma(ey, w1p[3], bbp[3]);                         \
        cc = __builtin_elementwise_fma(ex, w0p[3], cc);                             \
        t2 = unpack2((XW).w) + cc;                                                  \
        acc2[3] += __builtin_elementwise_max(t2, zero2);                            \
    }

    SG1_LOAD(0, 0)
    SG1_LOAD(1, 1)
    SG1_LOAD(2, 2)
    SG1_LOAD(3, 3)
    int i = 0;
    for (; i + 4 <= m; i += 4) {
        SG1_COMP(pk0, xw0) SG1_LOAD(0, i + 4)
        SG1_COMP(pk1, xw1) SG1_LOAD(1, i + 5)
        SG1_COMP(pk2, xw2) SG1_LOAD(2, i + 6)
        SG1_COMP(pk3, xw3) SG1_LOAD(3, i + 7)
    }
    if (i < m)     SG1_COMP(pk0, xw0)
    if (i + 1 < m) SG1_COMP(pk1, xw1)
    if (i + 2 < m) SG1_COMP(pk2, xw2)
    #undef SG1_LOAD
    #undef SG1_COMP

    float acc[8];
    #pragma unroll
    for (int p = 0; p < 4; ++p) { acc[2 * p] = acc2[p].x; acc[2 * p + 1] = acc2[p].y; }
    #pragma unroll
    for (int j = 0; j < 8; ++j) acc[j] += __shfl_xor(acc[j], 8);

    if (h == 0 && row < n) {
        float4 o0, o1;
        o0.x = acc[0] + xt0.x; o0.y = acc[1] + xt0.y; o0.z = acc[2] + xt0.z; o0.w = acc[3] + xt0.w;
        o1.x = acc[4] + xt1.x; o1.y = acc[5] + xt1.y; o1.z = acc[6] + xt1.z; o1.w = acc[7] + xt1.w;
        float4* hp = (float4*)&htile[r * HS + q * 8];
        hp[0] = o0; hp[1] = o1;
    }
    __syncthreads();

    // ---- fused mlp1 tail: waves 0,1 each process one 16-row MFMA tile ----
    if (wave < 2) {
        int t = wave;
        int quad = lane >> 4, col = lane & 15;
        float* lt = ltile + t * 16 * HS;

        bf8 Ah[2], Al[2];
        #pragma unroll
        for (int kh = 0; kh < 2; ++kh) {
            const float4* hr4 = (const float4*)&htile[(t * 16 + col) * HS + kh * 32 + quad * 8];
            float4 v0 = hr4[0], v1 = hr4[1];
            float av[8] = {v0.x, v0.y, v0.z, v0.w, v1.x, v1.y, v1.z, v1.w};
            bf8 th, tl;
            #pragma unroll
            for (int j = 0; j < 8; ++j) {
                unsigned short h1 = f2bf(av[j]);
                th[j] = (short)h1; tl[j] = (short)f2bf(av[j] - bf2f(h1));
            }
            Ah[kh] = th; Al[kh] = tl;
        }
        #pragma unroll
        for (int c4i = 0; c4i < 4; ++c4i) {
            int f0 = ((0 * 4 + c4i) * 4 + quad) * 16 + col;
            int f1 = ((1 * 4 + c4i) * 4 + quad) * 16 + col;
            bf8 wh0 = *(const bf8*)(wp + WP1AH + f0 * 8);
            bf8 wl0 = *(const bf8*)(wp + WP1AL + f0 * 8);
            bf8 wh1 = *(const bf8*)(wp + WP1AH + f1 * 8);
            bf8 wl1 = *(const bf8*)(wp + WP1AL + f1 * 8);
            f4 accm = {0.f, 0.f, 0.f, 0.f};
            accm = __builtin_amdgcn_mfma_f32_16x16x32_bf16(Ah[0], wh0, accm, 0, 0, 0);
            accm = __builtin_amdgcn_mfma_f32_16x16x32_bf16(Ah[0], wl0, accm, 0, 0, 0);
            accm = __builtin_amdgcn_mfma_f32_16x16x32_bf16(Al[0], wh0, accm, 0, 0, 0);
            accm = __builtin_amdgcn_mfma_f32_16x16x32_bf16(Ah[1], wh1, accm, 0, 0, 0);
            accm = __builtin_amdgcn_mfma_f32_16x16x32_bf16(Ah[1], wl1, accm, 0, 0, 0);
            accm = __builtin_amdgcn_mfma_f32_16x16x32_bf16(Al[1], wh1, accm, 0, 0, 0);
            float ba = b1a[c4i * 16 + col];
            #pragma unroll
            for (int rr = 0; rr < 4; ++rr)
                lt[(quad * 4 + rr) * HS + c4i * 16 + col] = fmaxf(accm[rr] + ba, 0.f);
        }
        bf8 A2h[2], A2l[2];
        #pragma unroll
        for (int kh = 0; kh < 2; ++kh) {
            const float4* lr4 = (const float4*)&lt[col * HS + kh * 32 + quad * 8];
            float4 v0 = lr4[0], v1 = lr4[1];
            float av[8] = {v0.x, v0.y, v0.z, v0.w, v1.x, v1.y, v1.z, v1.w};
            bf8 th, tl;
            #pragma unroll
            for (int j = 0; j < 8; ++j) {
                unsigned short h1 = f2bf(av[j]);
                th[j] = (short)h1; tl[j] = (short)f2bf(av[j] - bf2f(h1));
            }
            A2h[kh] = th; A2l[kh] = tl;
        }
        #pragma unroll
        for (int c4i = 0; c4i < 4; ++c4i) {
            int f0 = ((0 * 4 + c4i) * 4 + quad) * 16 + col;
            int f1 = ((1 * 4 + c4i) * 4 + quad) * 16 + col;
            bf8 wh0 = *(const bf8*)(wp + WP1BH + f0 * 8);
            bf8 wl0 = *(const bf8*)(wp + WP1BL + f0 * 8);
            bf8 wh1 = *(const bf8*)(wp + WP1BH + f1 * 8);
            bf8 wl1 = *(const bf8*)(wp + WP1BL + f1 * 8);
            f4 accm = {0.f, 0.f, 0.f, 0.f};
            accm = __builtin_amdgcn_mfma_f32_16x16x32_bf16(A2h[0], wh0, accm, 0, 0, 0);
            accm = __builtin_amdgcn_mfma_f32_16x16x32_bf16(A2h[0], wl0, accm, 0, 0, 0);
            accm = __builtin_amdgcn_mfma_f32_16x16x32_bf16(A2l[0], wh0, accm, 0, 0, 0);
            accm = __builtin_amdgcn_mfma_f32_16x16x32_bf16(A2h[1], wh1, accm, 0, 0, 0);
            accm = __builtin_amdgcn_mfma_f32_16x16x32_bf16(A2h[1], wl1, accm, 0, 0, 0);
            accm = __builtin_amdgcn_mfma_f32_16x16x32_bf16(A2l[1], wh1, accm, 0, 0, 0);
            float bb = b1b[c4i * 16 + col];
            #pragma unroll
            for (int rr = 0; rr < 4; ++rr)
                lt[(quad * 4 + rr) * HS + c4i * 16 + col] = accm[rr] + bb;
        }
        int rr = lane >> 2, cc2 = (lane & 3) * 16;
        unsigned o[8];
        #pragma unroll
        for (int j = 0; j < 8; ++j) {
            unsigned lo = f2bf(lt[rr * HS + cc2 + 2 * j]);
            unsigned hi = f2bf(lt[rr * HS + cc2 + 2 * j + 1]);
            o[j] = lo | (hi << 16);
        }
        uint4* dst = (uint4*)(x1b + (size_t)(b * ROWSB + t * 16 + rr) * F + cc2);
        dst[0] = make_uint4(o[0], o[1], o[2], o[3]);
        dst[1] = make_uint4(o[4], o[5], o[6], o[7]);
    }
}

// ================= sg2 + mlp2 fused: gather -> h2 (LDS) -> MFMA -> logits =================
__global__ __launch_bounds__(512) void sg2_kernel(
    const unsigned* __restrict__ keyA,
    const ushort* __restrict__ x1b,
    const float* __restrict__ x_actor,
    const int* __restrict__ gcursor,
    const ushort* __restrict__ wp,
    const float* __restrict__ b2a, const float* __restrict__ W2b,
    const float* __restrict__ b2b,
    float* __restrict__ out, int n)
{
    __shared__ unsigned lpay[CAP2];        // 5.5 KB
    __shared__ int hh[ROWSB], rst[ROWSB], cur[ROWSB];
    __shared__ float htile[ROWSB * HS];    // 8.7 KB
    int tid = threadIdx.x;
    int b = blockIdx.x;
    int cnt = min(gcursor[b], CAP2);
    const unsigned* ka = keyA + (size_t)b * CAP2;

    unsigned myk[3];
    #pragma unroll
    for (int j = 0; j < 3; ++j) {
        int idx = tid + 512 * j;
        if (idx < cnt) myk[j] = ka[idx];
    }
    if (tid < ROWSB) hh[tid] = 0;
    __syncthreads();
    #pragma unroll
    for (int j = 0; j < 3; ++j) {
        int idx = tid + 512 * j;
        if (idx < cnt) atomicAdd(&hh[myk[j] & 31u], 1);
    }
    __syncthreads();
    if (tid < 64) {
        int cc = (tid < ROWSB) ? hh[tid] : 0;
        int s = cc;
        #pragma unroll
        for (int off = 1; off < ROWSB; off <<= 1) {
            int u = __shfl_up(s, off);
            if (tid >= off) s += u;
        }
        if (tid < ROWSB) { rst[tid] = s - cc; cur[tid] = s - cc; }
    }
    __syncthreads();
    #pragma unroll
    for (int j = 0; j < 3; ++j) {
        int idx = tid + 512 * j;
        if (idx < cnt) {
            int p = atomicAdd(&cur[myk[j] & 31u], 1);
            lpay[p] = myk[j];
        }
    }
    __syncthreads();

    int wave = tid >> 6, lane = tid & 63;
    int q = lane & 7, g = lane >> 3;
    int gid = (wave << 3) | g;
    int r   = gid >> 1;
    int h   = gid & 1;
    int row = b * ROWSB + r;
    const fl2 zero2 = {0.f, 0.f};

    // hoisted x_actor row load (off the post-loop critical path)
    float4 xt0 = {0.f, 0.f, 0.f, 0.f}, xt1 = {0.f, 0.f, 0.f, 0.f};
    if (h == 0 && row < n) {
        const float4* xt = (const float4* __restrict__)(x_actor + (size_t)row * F + q * 8);
        xt0 = xt[0]; xt1 = xt[1];
    }

    int c  = hh[r];
    int m0 = (c + 1) >> 1;
    int sh = rst[r] + (h ? m0 : 0);
    int m  = h ? (c - m0) : m0;

    fl2 acc2[4];
    #pragma unroll
    for (int p = 0; p < 4; ++p) acc2[p] = zero2;

    uint4 xw0 = {0,0,0,0}, xw1 = {0,0,0,0}, xw2 = {0,0,0,0}, xw3 = {0,0,0,0};

    #define SG2_LOAD(J, K)                                                          \
    if ((K) < m) {                                                                  \
        unsigned t = lpay[sh + (K)];                                                \
        xw##J = ((const uint4* __restrict__)(x1b + ((size_t)(t >> 16) << 6)))[q];   \
    }

    #define SG2_COMP(XW)                                                            \
    {                                                                               \
        acc2[0] += unpack2((XW).x);                                                 \
        acc2[1] += unpack2((XW).y);                                                 \
        acc2[2] += unpack2((XW).z);                                                 \
        acc2[3] += unpack2((XW).w);                                                 \
    }

    SG2_LOAD(0, 0)
    SG2_LOAD(1, 1)
    SG2_LOAD(2, 2)
    SG2_LOAD(3, 3)
    int i = 0;
    for (; i + 4 <= m; i += 4) {
        SG2_COMP(xw0) SG2_LOAD(0, i + 4)
        SG2_COMP(xw1) SG2_LOAD(1, i + 5)
        SG2_COMP(xw2) SG2_LOAD(2, i + 6)
        SG2_COMP(xw3) SG2_LOAD(3, i + 7)
    }
    if (i < m)     SG2_COMP(xw0)
    if (i + 1 < m) SG2_COMP(xw1)
    if (i + 2 < m) SG2_COMP(xw2)
    #undef SG2_LOAD
    #undef SG2_COMP

    float acc[8];
    #pragma unroll
    for (int p = 0; p < 4; ++p) { acc[2 * p] = acc2[p].x; acc[2 * p + 1] = acc2[p].y; }
    #pragma unroll
    for (int j = 0; j < 8; ++j) acc[j] += __shfl_xor(acc[j], 8);

    if (h == 0 && row < n) {
        float4 o0, o1;
        o0.x = acc[0] + xt0.x; o0.y = acc[1] + xt0.y; o0.z = acc[2] + xt0.z; o0.w = acc[3] + xt0.w;
        o1.x = acc[4] + xt1.x; o1.y = acc[5] + xt1.y; o1.z = acc[6] + xt1.z; o1.w = acc[7] + xt1.w;
        float4* hp = (float4*)&htile[r * HS + q * 8];
        hp[0] = o0; hp[1] = o1;
    }
    __syncthreads();

    // ---- fused mlp2 tail: waves 0,1 each process one 16-row MFMA tile ----
    if (wave < 2) {
        int t = wave;
        int quad = lane >> 4, col = lane & 15;

        bf8 Ah[2], Al[2];
        #pragma unroll
        for (int kh = 0; kh < 2; ++kh) {
            const float4* hr4 = (const float4*)&htile[(t * 16 + col) * HS + kh * 32 + quad * 8];
            float4 v0 = hr4[0], v1 = hr4[1];
            float av[8] = {v0.x, v0.y, v0.z, v0.w, v1.x, v1.y, v1.z, v1.w};
            bf8 th, tl;
            #pragma unroll
            for (int j = 0; j < 8; ++j) {
                unsigned short h1 = f2bf(av[j]);
                th[j] = (short)h1; tl[j] = (short)f2bf(av[j] - bf2f(h1));
            }
            Ah[kh] = th; Al[kh] = tl;
        }

        float partial[4] = {0.f, 0.f, 0.f, 0.f};
        #pragma unroll
        for (int c4i = 0; c4i < 4; ++c4i) {
            int f0 = ((0 * 4 + c4i) * 4 + quad) * 16 + col;
            int f1 = ((1 * 4 + c4i) * 4 + quad) * 16 + col;
            bf8 wh0 = *(const bf8*)(wp + WP2AH + f0 * 8);
            bf8 wl0 = *(const bf8*)(wp + WP2AL + f0 * 8);
            bf8 wh1 = *(const bf8*)(wp + WP2AH + f1 * 8);
            bf8 wl1 = *(const bf8*)(wp + WP2AL + f1 * 8);
            f4 accm = {0.f, 0.f, 0.f, 0.f};
            accm = __builtin_amdgcn_mfma_f32_16x16x32_bf16(Ah[0], wh0, accm, 0, 0, 0);
            accm = __builtin_amdgcn_mfma_f32_16x16x32_bf16(Ah[0], wl0, accm, 0, 0, 0);
            accm = __builtin_amdgcn_mfma_f32_16x16x32_bf16(Al[0], wh0, accm, 0, 0, 0);
            accm = __builtin_amdgcn_mfma_f32_16x16x32_bf16(Ah[1], wh1, accm, 0, 0, 0);
            accm = __builtin_amdgcn_mfma_f32_16x16x32_bf16(Ah[1], wl1, accm, 0, 0, 0);
            accm = __builtin_amdgcn_mfma_f32_16x16x32_bf16(Al[1], wh1, accm, 0, 0, 0);
            float ba = b2a[c4i * 16 + col];
            float w_o = W2b[c4i * 16 + col];
            #pragma unroll
            for (int rr = 0; rr < 4; ++rr)
                partial[rr] += fmaxf(accm[rr] + ba, 0.f) * w_o;
        }
        #pragma unroll
        for (int off = 1; off < 16; off <<= 1)
            #pragma unroll
            for (int rr = 0; rr < 4; ++rr)
                partial[rr] += __shfl_xor(partial[rr], off);
        if (col == 0) {
            float bias2 = b2b[0];
            #pragma unroll
            for (int rr = 0; rr < 4; ++rr)
                out[b * ROWSB + t * 16 + quad * 4 + rr] = partial[rr] + bias2;
        }
    }
}

extern "C" void kernel_launch(void* const* d_in, const int* in_sizes, int n_in,
                              void* d_out, int out_size, void* d_ws, size_t ws_size,
                              hipStream_t stream)
{
    const float* x_state   = (const float*)d_in[0];
    const float* x_task    = (const float*)d_in[1];
    const float* x_actor   = (const float*)d_in[2];
    const float* edge_attr = (const float*)d_in[3];
    const float* We        = (const float*)d_in[4];
    const float* be        = (const float*)d_in[5];
    const float* W1a       = (const float*)d_in[6];
    const float* b1a       = (const float*)d_in[7];
    const float* W1b       = (const float*)d_in[8];
    const float* b1b       = (const float*)d_in[9];
    const float* W2a       = (const float*)d_in[10];
    const float* b2a       = (const float*)d_in[11];
    const float* W2b       = (const float*)d_in[12];
    const float* b2b       = (const float*)d_in[13];
    const int*   src_st    = (const int*)d_in[14];
    const int*   dst_st    = (const int*)d_in[15];
    const int*   src_ta    = (const int*)d_in[16];
    const int*   dst_ta    = (const int*)d_in[17];

    int n_state = in_sizes[0] / F;
    int n_task  = in_sizes[1] / F;
    int n_actor = in_sizes[2] / F;
    int E_st    = in_sizes[14];
    int E_ta    = in_sizes[16];

    // ---- workspace layout (~47 MB) ----
    ushort*   x1b   = (ushort*)d_ws;                            // 4 MB (bf16 x1)
    float*    hbig  = (float*)(x1b + (size_t)n_task * F);       // 8 MB region (wp carved from it)
    ushort*   wp    = (ushort*)hbig;                            // 48 KB hi/lo weight fragments
    ushort*   xsb   = (ushort*)(hbig + (size_t)n_task * F);     // 8 MB (bf16 x_state)
    uint2*    keyA1 = (uint2*)(xsb + (size_t)n_state * F);      // 21 MB
    unsigned* keyA2 = (unsigned*)(keyA1 + (size_t)NB * CAP1);   // 5.8 MB
    int*      cur1  = (int*)(keyA2 + (size_t)NB * CAP2);        // [1024]
    int*      cur2  = cur1 + NB;                                // [1024]

    int n4    = n_state * F / 4;
    int nCvt  = (n4 + 4095) / 4096;
    int nBin1 = (E_st + TILE - 1) / TILE;
    int nBin2 = (E_ta + TILE - 1) / TILE;

    hipMemsetAsync(cur1, 0, 2 * NB * sizeof(int), stream);
    prep_kernel<<<1 + nBin1 + nBin2 + nCvt, 1024, 0, stream>>>(
        (const float4*)x_state, (ushort4*)xsb, n4,
        src_st, dst_st, edge_attr, E_st, cur1, keyA1,
        src_ta, dst_ta, E_ta, cur2, keyA2,
        W1a, W1b, W2a, wp,
        nBin1, nBin2);
    sg1_kernel<<<NB, 512, 0, stream>>>(
        keyA1, xsb, x_task, We, be, cur1, wp, b1a, b1b, x1b, n_task);
    sg2_kernel<<<NB, 512, 0, stream>>>(
        keyA2, x1b, x_actor, cur2, wp, b2a, W2b, b2b, (float*)d_out, n_actor);
}